// Round 8
// baseline (345.010 us; speedup 1.0000x reference)
//
#include <hip/hip_runtime.h>
#include <math.h>

// Problem constants (setup_inputs: encodings [8192,64] f32, categorical [8192,25] f32, k=15)
#define Bsz    8192
#define Dd     64
#define NC     25
#define RT     64            // i-rows per block (main)
#define JT     64            // j-cols per tile
#define SPLITS 8             // j-range splits (1024 blocks = 128 rowgroups x 8)
#define TILES  (Bsz / SPLITS / JT)   // 16
#define KCAP   16            // >= k+1 (k clamped to 15)
#define RSU    136           // enc row stride in ushorts (272 B)
#define EPSf   1e-5f

typedef short  short8  __attribute__((ext_vector_type(8)));
typedef float  floatx4 __attribute__((ext_vector_type(4)));

// async global->LDS DMA: lane i deposits at (wave-uniform base)+i*size; flat-copy pattern only
#define GLD16(g, l) __builtin_amdgcn_global_load_lds((const __attribute__((address_space(1))) unsigned int*)(g), \
                     (__attribute__((address_space(3))) unsigned int*)(l), 16, 0, 0)
#define GLD4(g, l)  __builtin_amdgcn_global_load_lds((const __attribute__((address_space(1))) unsigned int*)(g), \
                     (__attribute__((address_space(3))) unsigned int*)(l), 4, 0, 0)

__device__ inline unsigned short f2bf(float x) {           // RNE f32 -> bf16 bits
    unsigned u = __float_as_uint(x);
    u += 0x7FFFu + ((u >> 16) & 1u);
    return (unsigned short)(u >> 16);
}
__device__ inline float bf2f(unsigned short h) { return __uint_as_float(((unsigned)h) << 16); }

// bitonic sort 16 regs ascending (unsigned); fully unrolled, compile-time directions
__device__ inline void bsort16(unsigned* a) {
    #pragma unroll
    for (int k = 2; k <= 16; k <<= 1)
        #pragma unroll
        for (int j = k >> 1; j > 0; j >>= 1)
            #pragma unroll
            for (int i = 0; i < 16; ++i) {
                int l = i ^ j;
                if (l > i) {
                    bool up = ((i & k) == 0) || (k == 16);
                    unsigned x = a[i], y = a[l];
                    unsigned lo = (x < y) ? x : y, hi = (x < y) ? y : x;
                    a[i] = up ? lo : hi;
                    a[l] = up ? hi : lo;
                }
            }
}
__device__ inline void bclean16(unsigned* t) {   // clean bitonic 16-seq to ascending
    #pragma unroll
    for (int j = 8; j > 0; j >>= 1)
        #pragma unroll
        for (int i = 0; i < 16; ++i) {
            int l = i ^ j;
            if (l > i) {
                unsigned x = t[i], y = t[l];
                t[i] = (x < y) ? x : y;
                t[l] = (x < y) ? y : x;
            }
        }
}
// keep-low-16 merge of two sorted-asc 16-lists: ls = lowest16(ls ∪ b), sorted asc
__device__ inline void bmerge16(unsigned* ls, const unsigned* b) {
    unsigned t[16];
    #pragma unroll
    for (int i = 0; i < 16; ++i) { unsigned x = ls[i], y = b[15 - i]; t[i] = (x < y) ? x : y; }
    bclean16(t);
    #pragma unroll
    for (int i = 0; i < 16; ++i) ls[i] = t[i];
}
__device__ inline void bmerge16_shfl(unsigned* ls, int mask) {   // partner via shfl_xor
    unsigned t[16];
    #pragma unroll
    for (int i = 0; i < 16; ++i) {
        unsigned pv = (unsigned)__shfl_xor((int)ls[15 - i], mask);
        unsigned x = ls[i];
        t[i] = (x < pv) ? x : pv;
    }
    bclean16(t);
    #pragma unroll
    for (int i = 0; i < 16; ++i) ls[i] = t[i];
}

// Output layout (f32, flat): [0..524287] encodings | [524288..532479] nbr entropy |
// [532480] cluster entropy | [532481] n_populated | [532482..540673] max_groups
//
// Workspace:
//   ctrl   @0      1024 B (memset 0): gc i32[32] @0 | pre_tick @128 | grp_tick i32[128] @192
//   slab   @4096   u32[8192]  (bits(sq)&~31 | label)
//   enc1   @36864  ushort[8192][136]  (e hi | lo | pad)   2.23 MB
//   enc2   @2265088  (-2e hi | lo | pad)                  2.23 MB
//   lists  @4493312  u32[8192][8][16]                     4 MB

__global__ __launch_bounds__(256) void pre_kernel(
    const float* __restrict__ enc, const float* __restrict__ cat,
    int* __restrict__ gc, int* __restrict__ pre_tick,
    unsigned int* __restrict__ slab,
    unsigned short* __restrict__ enc1, unsigned short* __restrict__ enc2,
    float* __restrict__ out_max, float* __restrict__ out_enc,
    float* __restrict__ out_glob)
{
    __shared__ int hist[32];
    __shared__ int winner;
    const int tid = threadIdx.x;
    const int gid = blockIdx.x * 256 + tid;       // 1024 x 256 = 262144
    const int p = gid >> 5, pr = gid & 31;        // 32 threads/row, 2 dims each
    if (tid < 32) hist[tid] = 0;

    // passthrough copy (1 float2 per thread, fully coalesced)
    ((float2*)out_enc)[gid] = ((const float2*)enc)[gid];

    float2 ev = ((const float2*)(enc + p * Dd))[pr];
    float s = ev.x * ev.x + ev.y * ev.y;
    #pragma unroll
    for (int m = 1; m < 32; m <<= 1) s += __shfl_xor(s, m, 32);   // row ssq

    // hi/lo bf16 splits of e (enc1) and -2e (enc2)
    {
        unsigned* d1 = (unsigned*)(enc1 + (size_t)p * RSU);
        unsigned* d2 = (unsigned*)(enc2 + (size_t)p * RSU);
        unsigned short ha = f2bf(ev.x), hb = f2bf(ev.y);
        unsigned short la = f2bf(ev.x - bf2f(ha)), lb = f2bf(ev.y - bf2f(hb));
        d1[pr]      = (unsigned)ha | ((unsigned)hb << 16);
        d1[32 + pr] = (unsigned)la | ((unsigned)lb << 16);
        float y0 = -2.f * ev.x, y1 = -2.f * ev.y;
        unsigned short hc = f2bf(y0), hd = f2bf(y1);
        unsigned short lc = f2bf(y0 - bf2f(hc)), ld = f2bf(y1 - bf2f(hd));
        d2[pr]      = (unsigned)hc | ((unsigned)hd << 16);
        d2[32 + pr] = (unsigned)lc | ((unsigned)ld << 16);
        // pad uints 64..67 are DMA-copied but never read by fragments
    }
    // categorical argmax across 32 lanes (first-max: ties -> min index; cat >= 0 so -1 sentinel safe)
    float cv = (pr < NC) ? cat[p * NC + pr] : -1.f;
    int ci = pr;
    #pragma unroll
    for (int m = 1; m < 32; m <<= 1) {
        float ov = __shfl_xor(cv, m, 32);
        int   oi = __shfl_xor(ci, m, 32);
        if (ov > cv || (ov == cv && oi < ci)) { cv = ov; ci = oi; }
    }
    __syncthreads();   // hist zero visible
    if (pr == 0) {
        out_max[p] = cv;
        slab[p] = (__float_as_uint(s) & ~31u) | (unsigned)ci;  // sq trunc 2^-18 rel, harmless
        atomicAdd(&hist[ci], 1);                               // 8 rows/block
    }
    __syncthreads();
    if (tid < NC && hist[tid]) atomicAdd(&gc[tid], hist[tid]);
    __threadfence();
    __syncthreads();
    if (tid == 0) winner = atomicAdd(pre_tick, 1);
    __syncthreads();
    if (winner == 1023 && tid == 0) {   // last block: all gc contributions visible
        __threadfence();
        float gent = 0.f, npop = 0.f;
        for (int i = 0; i < NC; ++i) {
            int g = atomicAdd(&gc[i], 0);   // RMW read at the coherent point
            if (g > 0) {
                npop += 1.f;
                float gb = (float)g / (float)Bsz;
                gent -= gb * logf(gb + EPSf);
            }
        }
        out_glob[0] = gent;
        out_glob[1] = npop;
    }
}

__global__ __launch_bounds__(256, 4) void main_kernel(
    const unsigned short* __restrict__ enc1, const unsigned short* __restrict__ enc2,
    const unsigned int* __restrict__ slab, unsigned int* __restrict__ lists,
    int* __restrict__ grp_tick, const int* __restrict__ kptr,
    float* __restrict__ out_ent)
{
    __shared__ __align__(16) unsigned short Ai[RT * RSU];   // 17408 B i-tile (enc1), persists
    __shared__ __align__(16) unsigned short Bj[JT * RSU];   // 17408 B j-tile (enc2), restaged per tile
    __shared__ __align__(16) unsigned int   slds[JT];       // 256 B j-tile slab
    __shared__ int winflag;
    // ~35.3 KB -> 4 blocks/CU (16 waves/CU)

    const int tid  = threadIdx.x;
    const int wv   = tid >> 6, lane = tid & 63;
    const int quad = (tid >> 4) & 3, c15 = tid & 15;
    const int rowgrp = blockIdx.x >> 3, s = blockIdx.x & 7;
    const int rowbase = rowgrp * RT;
    const int jb0 = s * (Bsz / SPLITS);

    // ---- stage i-tile + j-tile 0 + slab 0 via async DMA (flat copies) ----
    {
        const char* gi = (const char*)(enc1 + (size_t)rowbase * RSU);
        const char* gj = (const char*)(enc2 + (size_t)jb0 * RSU);
        char* li = (char*)Ai; char* lj = (char*)Bj;
        for (int c = wv; c < 17; c += 4) GLD16(gi + c * 1024 + lane * 16, li + c * 1024 + lane * 16);
        for (int c = wv; c < 17; c += 4) GLD16(gj + c * 1024 + lane * 16, lj + c * 1024 + lane * 16);
        if (wv == 3) GLD4((const char*)(slab + jb0) + lane * 4, (char*)slds + lane * 4);
    }
    const float sqi = __uint_as_float(slab[rowbase + 16 * wv + c15] & ~31u);
    __syncthreads();   // drains vmcnt -> tiles visible

    short8 bh[2], bl[2];   // hoisted i-fragments (Ai persists): B-operand, row = 16*wv + c15
    #pragma unroll
    for (int c = 0; c < 2; ++c) {
        bh[c] = *(const short8*)&Ai[(16 * wv + c15) * RSU + quad * 8 + c * 32];
        bl[c] = *(const short8*)&Ai[(16 * wv + c15) * RSU + 64 + quad * 8 + c * 32];
    }

    unsigned int ls[KCAP];   // per-thread sorted-ascending top-16: bits(d2)&~31 | label
    #pragma unroll
    for (int q = 0; q < KCAP; ++q) ls[q] = 0xFFFFFFFFu;

    for (int t = 0; t < TILES; ++t) {
        // ---- MFMA: C[m=j][n=i]; acc[nt] covers j-sub nt; j = jb + 16nt + 4quad + r ----
        floatx4 acc[4];
        #pragma unroll
        for (int nt = 0; nt < 4; ++nt) acc[nt] = (floatx4){0.f, 0.f, 0.f, 0.f};
        #pragma unroll
        for (int nt = 0; nt < 4; ++nt) {
            #pragma unroll
            for (int c = 0; c < 2; ++c) {
                short8 ah = *(const short8*)&Bj[(16 * nt + c15) * RSU + quad * 8 + c * 32];
                short8 al = *(const short8*)&Bj[(16 * nt + c15) * RSU + 64 + quad * 8 + c * 32];
                acc[nt] = __builtin_amdgcn_mfma_f32_16x16x32_bf16(ah, bh[c], acc[nt], 0, 0, 0);
                acc[nt] = __builtin_amdgcn_mfma_f32_16x16x32_bf16(ah, bl[c], acc[nt], 0, 0, 0);
                acc[nt] = __builtin_amdgcn_mfma_f32_16x16x32_bf16(al, bh[c], acc[nt], 0, 0, 0);
            }
        }
        unsigned cand[16];   // pack candidates (reads slds of tile t — before S_a)
        #pragma unroll
        for (int nt = 0; nt < 4; ++nt) {
            uint4 sv = *(const uint4*)&slds[16 * nt + 4 * quad];
            unsigned slr[4] = {sv.x, sv.y, sv.z, sv.w};
            #pragma unroll
            for (int r = 0; r < 4; ++r) {
                unsigned sl = slr[r];
                float d2 = fmaxf(sqi + __uint_as_float(sl & ~31u) + acc[nt][r], 0.f);
                cand[4 * nt + r] = (__float_as_uint(d2) & ~31u) | (sl & 31u);
            }
        }
        __syncthreads();   // S_a: all waves done reading Bj/slds of tile t
        if (t + 1 < TILES) {   // next tile's DMA; sort/merge overlaps the flight
            const char* gj = (const char*)(enc2 + (size_t)(jb0 + (t + 1) * JT) * RSU);
            char* lj = (char*)Bj;
            for (int c = wv; c < 17; c += 4) GLD16(gj + c * 1024 + lane * 16, lj + c * 1024 + lane * 16);
            if (wv == 3) GLD4((const char*)(slab + jb0 + (t + 1) * JT) + lane * 4, (char*)slds + lane * 4);
        }
        bsort16(cand);       // branchless selection
        bmerge16(ls, cand);
        __syncthreads();   // S_b: DMA drained, tile t+1 visible
    }

    bmerge16_shfl(ls, 16);   // quad ^ 1
    bmerge16_shfl(ls, 32);   // quad ^ 2 -> row/split sorted top-16 in all quads
    if (quad == 0) {
        uint4* outl = (uint4*)(lists + ((unsigned)(rowbase + 16 * wv + c15) * SPLITS + s) * KCAP);
        outl[0] = make_uint4(ls[0],  ls[1],  ls[2],  ls[3]);
        outl[1] = make_uint4(ls[4],  ls[5],  ls[6],  ls[7]);
        outl[2] = make_uint4(ls[8],  ls[9],  ls[10], ls[11]);
        outl[3] = make_uint4(ls[12], ls[13], ls[14], ls[15]);
    }

    // ---- ticket: 8th finisher of this rowgroup merges all splits for its 64 rows ----
    __threadfence();       // release this block's lists writes (device scope)
    __syncthreads();       // + vmcnt drain: all lanes' stores complete before ticket
    if (tid == 0) winflag = (atomicAdd(&grp_tick[rowgrp], 1) == SPLITS - 1);
    __syncthreads();
    if (!winflag) return;
    __threadfence();       // acquire: other blocks' lists writes

    {
        const int row = rowbase + (tid >> 2), sub = tid & 3;   // 64 rows x 4 subs
        unsigned A[16], Bv[16];
        {
            const uint4* src = (const uint4*)(lists + (unsigned)row * (SPLITS * KCAP) + sub * 32);
            #pragma unroll
            for (int i = 0; i < 4; ++i) {
                uint4 v = src[i];
                A[4*i] = v.x; A[4*i+1] = v.y; A[4*i+2] = v.z; A[4*i+3] = v.w;
            }
            #pragma unroll
            for (int i = 0; i < 4; ++i) {
                uint4 v = src[4 + i];
                Bv[4*i] = v.x; Bv[4*i+1] = v.y; Bv[4*i+2] = v.z; Bv[4*i+3] = v.w;
            }
        }
        bmerge16(A, Bv);
        bmerge16_shfl(A, 1);   // sub ^ 1
        bmerge16_shfl(A, 2);   // sub ^ 2 -> row's global sorted top-16 in all subs

        int kk = kptr[0];
        if (kk > Bsz / 4) kk = Bsz / 4;
        if (kk > KCAP - 1) kk = KCAP - 1;

        unsigned kth = A[15];
        #pragma unroll
        for (int q = 0; q < 16; ++q) if (q == kk) kth = A[q];
        int nn = 0;
        #pragma unroll
        for (int t = 0; t < 15; ++t) nn += (t < kk && A[t] < kth) ? 1 : 0;  // strict <, sorted prefix

        float inv = 1.f / (float)((nn > 0) ? nn : 1);
        float part = 0.f;
        #pragma unroll
        for (int a4 = 0; a4 < 4; ++a4) {
            int a = sub + 4 * a4;
            if (a < nn) {
                int la = (int)(A[a] & 31u);
                int c = 0;
                #pragma unroll
                for (int b = 0; b < 15; ++b) c += (b < nn && (int)(A[b] & 31u) == la) ? 1 : 0;
                part -= inv * logf((float)c * inv + EPSf);
            }
        }
        part += __shfl_xor(part, 1);
        part += __shfl_xor(part, 2);
        if (sub == 0) out_ent[row] = part;
    }
}

extern "C" void kernel_launch(void* const* d_in, const int* in_sizes, int n_in,
                              void* d_out, int out_size, void* d_ws, size_t ws_size,
                              hipStream_t stream)
{
    const float* enc  = (const float*)d_in[0];
    const float* cat  = (const float*)d_in[1];
    const int*   kptr = (const int*)d_in[2];
    float* out = (float*)d_out;

    int*            gc       = (int*)d_ws;
    int*            pre_tick = (int*)((char*)d_ws + 128);
    int*            grp_tick = (int*)((char*)d_ws + 192);
    unsigned int*   slab     = (unsigned int*)((char*)d_ws + 4096);
    unsigned short* enc1     = (unsigned short*)((char*)d_ws + 36864);
    unsigned short* enc2     = (unsigned short*)((char*)d_ws + 2265088);
    unsigned int*   lists    = (unsigned int*)((char*)d_ws + 4493312);

    float* out_enc  = out;
    float* out_ent  = out + Bsz * Dd;                 // 524288
    float* out_glob = out + Bsz * Dd + Bsz;           // 532480 (entropy, n_populated)
    float* out_max  = out + Bsz * Dd + Bsz + 2;       // 532482

    hipMemsetAsync(d_ws, 0, 1024, stream);            // gc + tickets
    pre_kernel<<<1024, 256, 0, stream>>>(enc, cat, gc, pre_tick, slab, enc1, enc2,
                                         out_max, out_enc, out_glob);
    main_kernel<<<(Bsz / RT) * SPLITS, 256, 0, stream>>>(enc1, enc2, slab, lists,
                                                         grp_tick, kptr, out_ent);
}

// Round 9
// 129.450 us; speedup vs baseline: 2.6652x; 2.6652x over previous
//
#include <hip/hip_runtime.h>
#include <math.h>

// Problem constants (setup_inputs: encodings [8192,64] f32, categorical [8192,25] f32, k=15)
#define Bsz    8192
#define Dd     64
#define NC     25
#define RT     64            // i-rows per block (main)
#define JT     64            // j-cols per tile
#define SPLITS 8             // j-range splits (1024 blocks = 128 rowgroups x 8)
#define TILES  (Bsz / SPLITS / JT)   // 16
#define KCAP   16            // >= k+1 (k clamped to 15)
#define RSU    136           // enc row stride in ushorts (272 B)
#define EPSf   1e-5f

typedef short  short8  __attribute__((ext_vector_type(8)));
typedef float  floatx4 __attribute__((ext_vector_type(4)));

// async global->LDS DMA: lane i deposits at (wave-uniform base)+i*size; flat-copy pattern only
#define GLD16(g, l) __builtin_amdgcn_global_load_lds((const __attribute__((address_space(1))) unsigned int*)(g), \
                     (__attribute__((address_space(3))) unsigned int*)(l), 16, 0, 0)
#define GLD4(g, l)  __builtin_amdgcn_global_load_lds((const __attribute__((address_space(1))) unsigned int*)(g), \
                     (__attribute__((address_space(3))) unsigned int*)(l), 4, 0, 0)

__device__ inline unsigned short f2bf(float x) {           // RNE f32 -> bf16 bits
    unsigned u = __float_as_uint(x);
    u += 0x7FFFu + ((u >> 16) & 1u);
    return (unsigned short)(u >> 16);
}
__device__ inline float bf2f(unsigned short h) { return __uint_as_float(((unsigned)h) << 16); }

// bitonic sort 16 regs ascending (unsigned); fully unrolled, compile-time directions
__device__ inline void bsort16(unsigned* a) {
    #pragma unroll
    for (int k = 2; k <= 16; k <<= 1)
        #pragma unroll
        for (int j = k >> 1; j > 0; j >>= 1)
            #pragma unroll
            for (int i = 0; i < 16; ++i) {
                int l = i ^ j;
                if (l > i) {
                    bool up = ((i & k) == 0) || (k == 16);
                    unsigned x = a[i], y = a[l];
                    unsigned lo = (x < y) ? x : y, hi = (x < y) ? y : x;
                    a[i] = up ? lo : hi;
                    a[l] = up ? hi : lo;
                }
            }
}
__device__ inline void bclean16(unsigned* t) {   // clean bitonic 16-seq to ascending
    #pragma unroll
    for (int j = 8; j > 0; j >>= 1)
        #pragma unroll
        for (int i = 0; i < 16; ++i) {
            int l = i ^ j;
            if (l > i) {
                unsigned x = t[i], y = t[l];
                t[i] = (x < y) ? x : y;
                t[l] = (x < y) ? y : x;
            }
        }
}
// keep-low-16 merge of two sorted-asc 16-lists: ls = lowest16(ls ∪ b), sorted asc
__device__ inline void bmerge16(unsigned* ls, const unsigned* b) {
    unsigned t[16];
    #pragma unroll
    for (int i = 0; i < 16; ++i) { unsigned x = ls[i], y = b[15 - i]; t[i] = (x < y) ? x : y; }
    bclean16(t);
    #pragma unroll
    for (int i = 0; i < 16; ++i) ls[i] = t[i];
}
__device__ inline void bmerge16_shfl(unsigned* ls, int mask) {   // partner via shfl_xor
    unsigned t[16];
    #pragma unroll
    for (int i = 0; i < 16; ++i) {
        unsigned pv = (unsigned)__shfl_xor((int)ls[15 - i], mask);
        unsigned x = ls[i];
        t[i] = (x < pv) ? x : pv;
    }
    bclean16(t);
    #pragma unroll
    for (int i = 0; i < 16; ++i) ls[i] = t[i];
}

// Output layout (f32, flat): [0..524287] encodings | [524288..532479] nbr entropy |
// [532480] cluster entropy | [532481] n_populated | [532482..540673] max_groups
//
// Workspace: slab u32[8192] @0 (bits(sq)&~31|label) | enc1 ushort[8192][136] @32768
//   (e hi|lo|pad) | enc2 @2260992 (-2e hi|lo|pad) | lists u32[8192][8][16] @4489216
// No control words -> no memset dispatch, no device-scope fences anywhere.

__global__ __launch_bounds__(256) void pre_kernel(
    const float* __restrict__ enc, const float* __restrict__ cat,
    unsigned int* __restrict__ slab,
    unsigned short* __restrict__ enc1, unsigned short* __restrict__ enc2,
    float* __restrict__ out_max, float* __restrict__ out_enc)
{
    const int gid = blockIdx.x * 256 + threadIdx.x;   // 1024 x 256 = 262144
    const int p = gid >> 5, pr = gid & 31;            // 32 threads/row, 2 dims each

    // passthrough copy (1 float2 per thread, fully coalesced)
    ((float2*)out_enc)[gid] = ((const float2*)enc)[gid];

    float2 ev = ((const float2*)(enc + p * Dd))[pr];
    float s = ev.x * ev.x + ev.y * ev.y;
    #pragma unroll
    for (int m = 1; m < 32; m <<= 1) s += __shfl_xor(s, m, 32);   // row ssq

    // hi/lo bf16 splits of e (enc1) and -2e (enc2)
    {
        unsigned* d1 = (unsigned*)(enc1 + (size_t)p * RSU);
        unsigned* d2 = (unsigned*)(enc2 + (size_t)p * RSU);
        unsigned short ha = f2bf(ev.x), hb = f2bf(ev.y);
        unsigned short la = f2bf(ev.x - bf2f(ha)), lb = f2bf(ev.y - bf2f(hb));
        d1[pr]      = (unsigned)ha | ((unsigned)hb << 16);
        d1[32 + pr] = (unsigned)la | ((unsigned)lb << 16);
        float y0 = -2.f * ev.x, y1 = -2.f * ev.y;
        unsigned short hc = f2bf(y0), hd = f2bf(y1);
        unsigned short lc = f2bf(y0 - bf2f(hc)), ld = f2bf(y1 - bf2f(hd));
        d2[pr]      = (unsigned)hc | ((unsigned)hd << 16);
        d2[32 + pr] = (unsigned)lc | ((unsigned)ld << 16);
        // pad uints 64..67 are DMA-copied but never read by fragments
    }
    // categorical argmax across 32 lanes (first-max: ties -> min index; cat >= 0 so -1 sentinel safe)
    float cv = (pr < NC) ? cat[p * NC + pr] : -1.f;
    int ci = pr;
    #pragma unroll
    for (int m = 1; m < 32; m <<= 1) {
        float ov = __shfl_xor(cv, m, 32);
        int   oi = __shfl_xor(ci, m, 32);
        if (ov > cv || (ov == cv && oi < ci)) { cv = ov; ci = oi; }
    }
    if (pr == 0) {
        out_max[p] = cv;
        slab[p] = (__float_as_uint(s) & ~31u) | (unsigned)ci;  // sq trunc 2^-18 rel, harmless
    }
}

__global__ __launch_bounds__(256, 4) void main_kernel(
    const unsigned short* __restrict__ enc1, const unsigned short* __restrict__ enc2,
    const unsigned int* __restrict__ slab, unsigned int* __restrict__ lists)
{
    __shared__ __align__(16) unsigned short Ai[RT * RSU];   // 17408 B i-tile (enc1), persists
    __shared__ __align__(16) unsigned short Bj[JT * RSU];   // 17408 B j-tile (enc2), restaged per tile
    __shared__ __align__(16) unsigned int   slds[JT];       // 256 B j-tile slab
    // ~35.3 KB -> 4 blocks/CU (16 waves/CU)

    const int tid  = threadIdx.x;
    const int wv   = tid >> 6, lane = tid & 63;
    const int quad = (tid >> 4) & 3, c15 = tid & 15;
    const int rowgrp = blockIdx.x >> 3, s = blockIdx.x & 7;
    const int rowbase = rowgrp * RT;
    const int jb0 = s * (Bsz / SPLITS);

    // ---- stage i-tile + j-tile 0 + slab 0 via async DMA (flat copies) ----
    {
        const char* gi = (const char*)(enc1 + (size_t)rowbase * RSU);
        const char* gj = (const char*)(enc2 + (size_t)jb0 * RSU);
        char* li = (char*)Ai; char* lj = (char*)Bj;
        for (int c = wv; c < 17; c += 4) GLD16(gi + c * 1024 + lane * 16, li + c * 1024 + lane * 16);
        for (int c = wv; c < 17; c += 4) GLD16(gj + c * 1024 + lane * 16, lj + c * 1024 + lane * 16);
        if (wv == 3) GLD4((const char*)(slab + jb0) + lane * 4, (char*)slds + lane * 4);
    }
    const float sqi = __uint_as_float(slab[rowbase + 16 * wv + c15] & ~31u);
    __syncthreads();   // drains vmcnt -> tiles visible

    short8 bh[2], bl[2];   // hoisted i-fragments (Ai persists): B-operand, row = 16*wv + c15
    #pragma unroll
    for (int c = 0; c < 2; ++c) {
        bh[c] = *(const short8*)&Ai[(16 * wv + c15) * RSU + quad * 8 + c * 32];
        bl[c] = *(const short8*)&Ai[(16 * wv + c15) * RSU + 64 + quad * 8 + c * 32];
    }

    unsigned int ls[KCAP];   // per-thread sorted-ascending top-16: bits(d2)&~31 | label
    #pragma unroll
    for (int q = 0; q < KCAP; ++q) ls[q] = 0xFFFFFFFFu;

    for (int t = 0; t < TILES; ++t) {
        // ---- MFMA: C[m=j][n=i]; acc[nt] covers j-sub nt; j = jb + 16nt + 4quad + r ----
        floatx4 acc[4];
        #pragma unroll
        for (int nt = 0; nt < 4; ++nt) acc[nt] = (floatx4){0.f, 0.f, 0.f, 0.f};
        #pragma unroll
        for (int nt = 0; nt < 4; ++nt) {
            #pragma unroll
            for (int c = 0; c < 2; ++c) {
                short8 ah = *(const short8*)&Bj[(16 * nt + c15) * RSU + quad * 8 + c * 32];
                short8 al = *(const short8*)&Bj[(16 * nt + c15) * RSU + 64 + quad * 8 + c * 32];
                acc[nt] = __builtin_amdgcn_mfma_f32_16x16x32_bf16(ah, bh[c], acc[nt], 0, 0, 0);
                acc[nt] = __builtin_amdgcn_mfma_f32_16x16x32_bf16(ah, bl[c], acc[nt], 0, 0, 0);
                acc[nt] = __builtin_amdgcn_mfma_f32_16x16x32_bf16(al, bh[c], acc[nt], 0, 0, 0);
            }
        }
        unsigned cand[16];   // pack candidates (reads slds of tile t — before S_a)
        #pragma unroll
        for (int nt = 0; nt < 4; ++nt) {
            uint4 sv = *(const uint4*)&slds[16 * nt + 4 * quad];
            unsigned slr[4] = {sv.x, sv.y, sv.z, sv.w};
            #pragma unroll
            for (int r = 0; r < 4; ++r) {
                unsigned sl = slr[r];
                float d2 = fmaxf(sqi + __uint_as_float(sl & ~31u) + acc[nt][r], 0.f);
                cand[4 * nt + r] = (__float_as_uint(d2) & ~31u) | (sl & 31u);
            }
        }
        __syncthreads();   // S_a: all waves done reading Bj/slds of tile t
        if (t + 1 < TILES) {   // next tile's DMA; sort/merge overlaps the flight
            const char* gj = (const char*)(enc2 + (size_t)(jb0 + (t + 1) * JT) * RSU);
            char* lj = (char*)Bj;
            for (int c = wv; c < 17; c += 4) GLD16(gj + c * 1024 + lane * 16, lj + c * 1024 + lane * 16);
            if (wv == 3) GLD4((const char*)(slab + jb0 + (t + 1) * JT) + lane * 4, (char*)slds + lane * 4);
        }
        bsort16(cand);       // branchless selection
        bmerge16(ls, cand);
        __syncthreads();   // S_b: DMA drained, tile t+1 visible
    }

    bmerge16_shfl(ls, 16);   // quad ^ 1
    bmerge16_shfl(ls, 32);   // quad ^ 2 -> row/split sorted top-16 in all quads
    if (quad == 0) {
        uint4* outl = (uint4*)(lists + ((unsigned)(rowbase + 16 * wv + c15) * SPLITS + s) * KCAP);
        outl[0] = make_uint4(ls[0],  ls[1],  ls[2],  ls[3]);
        outl[1] = make_uint4(ls[4],  ls[5],  ls[6],  ls[7]);
        outl[2] = make_uint4(ls[8],  ls[9],  ls[10], ls[11]);
        outl[3] = make_uint4(ls[12], ls[13], ls[14], ls[15]);
    }
}

__global__ __launch_bounds__(256) void merge_kernel(
    const unsigned int* __restrict__ lists, const int* __restrict__ kptr,
    const unsigned int* __restrict__ slab,
    float* __restrict__ out_ent, float* __restrict__ out_glob)
{
    __shared__ int cnt[32];
    const int g = blockIdx.x * 256 + threadIdx.x;   // 128 x 256 = 32768
    const int row = g >> 2, sub = g & 3;            // 4 threads per row

    // each sub merges its two sorted lists (global top-16 ⊆ union of pairwise top-16s)
    unsigned A[16], Bv[16];
    {
        const uint4* src = (const uint4*)(lists + (unsigned)row * (SPLITS * KCAP) + sub * 32);
        #pragma unroll
        for (int i = 0; i < 4; ++i) {
            uint4 v = src[i];
            A[4*i] = v.x; A[4*i+1] = v.y; A[4*i+2] = v.z; A[4*i+3] = v.w;
        }
        #pragma unroll
        for (int i = 0; i < 4; ++i) {
            uint4 v = src[4 + i];
            Bv[4*i] = v.x; Bv[4*i+1] = v.y; Bv[4*i+2] = v.z; Bv[4*i+3] = v.w;
        }
    }
    bmerge16(A, Bv);
    bmerge16_shfl(A, 1);   // sub ^ 1
    bmerge16_shfl(A, 2);   // sub ^ 2 -> row's global sorted top-16 in all subs

    int kk = kptr[0];
    if (kk > Bsz / 4) kk = Bsz / 4;
    if (kk > KCAP - 1) kk = KCAP - 1;

    unsigned kth = A[15];
    #pragma unroll
    for (int q = 0; q < 16; ++q) if (q == kk) kth = A[q];
    int nn = 0;
    #pragma unroll
    for (int t = 0; t < 15; ++t) nn += (t < kk && A[t] < kth) ? 1 : 0;  // strict <, sorted prefix

    float inv = 1.f / (float)((nn > 0) ? nn : 1);
    float part = 0.f;
    #pragma unroll
    for (int a4 = 0; a4 < 4; ++a4) {
        int a = sub + 4 * a4;
        if (a < nn) {
            int la = (int)(A[a] & 31u);
            int c = 0;
            #pragma unroll
            for (int b = 0; b < 15; ++b) c += (b < nn && (int)(A[b] & 31u) == la) ? 1 : 0;
            part -= inv * logf((float)c * inv + EPSf);
        }
    }
    part += __shfl_xor(part, 1);
    part += __shfl_xor(part, 2);
    if (sub == 0) out_ent[row] = part;

    // block 0: global label histogram from slab (LDS atomics) + cluster entropy
    if (blockIdx.x == 0) {   // block-uniform branch: barriers legal
        const int tid = threadIdx.x;
        if (tid < 32) cnt[tid] = 0;
        __syncthreads();
        for (int i = tid; i < Bsz; i += 256) atomicAdd(&cnt[slab[i] & 31u], 1);
        __syncthreads();
        if (tid == 0) {
            float gent = 0.f, npop = 0.f;
            for (int i = 0; i < NC; ++i) {
                int gcv = cnt[i];
                if (gcv > 0) {
                    npop += 1.f;
                    float gb = (float)gcv / (float)Bsz;
                    gent -= gb * logf(gb + EPSf);
                }
            }
            out_glob[0] = gent;
            out_glob[1] = npop;
        }
    }
}

extern "C" void kernel_launch(void* const* d_in, const int* in_sizes, int n_in,
                              void* d_out, int out_size, void* d_ws, size_t ws_size,
                              hipStream_t stream)
{
    const float* enc  = (const float*)d_in[0];
    const float* cat  = (const float*)d_in[1];
    const int*   kptr = (const int*)d_in[2];
    float* out = (float*)d_out;

    unsigned int*   slab  = (unsigned int*)d_ws;
    unsigned short* enc1  = (unsigned short*)((char*)d_ws + 32768);
    unsigned short* enc2  = (unsigned short*)((char*)d_ws + 2260992);
    unsigned int*   lists = (unsigned int*)((char*)d_ws + 4489216);

    float* out_enc  = out;
    float* out_ent  = out + Bsz * Dd;                 // 524288
    float* out_glob = out + Bsz * Dd + Bsz;           // 532480 (entropy, n_populated)
    float* out_max  = out + Bsz * Dd + Bsz + 2;       // 532482

    pre_kernel<<<1024, 256, 0, stream>>>(enc, cat, slab, enc1, enc2, out_max, out_enc);
    main_kernel<<<(Bsz / RT) * SPLITS, 256, 0, stream>>>(enc1, enc2, slab, lists);
    merge_kernel<<<128, 256, 0, stream>>>(lists, kptr, slab, out_ent, out_glob);
}